// Round 1
// baseline (1096.466 us; speedup 1.0000x reference)
//
#include <hip/hip_runtime.h>
#include <hip/hip_bf16.h>

#define D_MODEL 1024
#define S_LEN   2048
#define NBATCH  2
#define NHEADS  16
#define HDIM    64
#define DQKV    3072   // 3 * D_MODEL

// ---------------------------------------------------------------------------
// C[M][N] = A[M][K] * W[N][K]^T + bias[N]   (f32, 128x128 tile, BK=16)
// 256 threads, each computes 8x8. LDS tiles stored k-major [16][132] so the
// inner loop reads float4 fragments (ds_read_b128, 2-way conflicts = free).
// ---------------------------------------------------------------------------
__global__ __launch_bounds__(256) void gemm_bias_kernel(
    const float* __restrict__ A, const float* __restrict__ W,
    const float* __restrict__ bias, float* __restrict__ C,
    int M, int N, int K)
{
    __shared__ float As[16][132];
    __shared__ float Bs[16][132];

    const int tid = threadIdx.x;
    const int tx  = tid & 15;        // col group
    const int ty  = tid >> 4;        // row group
    const int bm  = blockIdx.y * 128;
    const int bn  = blockIdx.x * 128;

    const int lm  = tid >> 1;        // 0..127 : tile row loaded by this thread
    const int lk8 = (tid & 1) * 8;   // 0 or 8 : k-offset

    const float* Arow = A + (size_t)(bm + lm) * K + lk8;
    const float* Wrow = W + (size_t)(bn + lm) * K + lk8;

    float acc[8][8] = {};

    for (int k0 = 0; k0 < K; k0 += 16) {
        float4 a0 = *(const float4*)(Arow + k0);
        float4 a1 = *(const float4*)(Arow + k0 + 4);
        float4 b0 = *(const float4*)(Wrow + k0);
        float4 b1 = *(const float4*)(Wrow + k0 + 4);
        __syncthreads();   // previous compute done, LDS free
        As[lk8+0][lm] = a0.x; As[lk8+1][lm] = a0.y; As[lk8+2][lm] = a0.z; As[lk8+3][lm] = a0.w;
        As[lk8+4][lm] = a1.x; As[lk8+5][lm] = a1.y; As[lk8+6][lm] = a1.z; As[lk8+7][lm] = a1.w;
        Bs[lk8+0][lm] = b0.x; Bs[lk8+1][lm] = b0.y; Bs[lk8+2][lm] = b0.z; Bs[lk8+3][lm] = b0.w;
        Bs[lk8+4][lm] = b1.x; Bs[lk8+5][lm] = b1.y; Bs[lk8+6][lm] = b1.z; Bs[lk8+7][lm] = b1.w;
        __syncthreads();
        #pragma unroll
        for (int k = 0; k < 16; ++k) {
            float4 av0 = *(const float4*)&As[k][ty*8];
            float4 av1 = *(const float4*)&As[k][ty*8+4];
            float4 bv0 = *(const float4*)&Bs[k][tx*8];
            float4 bv1 = *(const float4*)&Bs[k][tx*8+4];
            float a[8] = {av0.x,av0.y,av0.z,av0.w,av1.x,av1.y,av1.z,av1.w};
            float b[8] = {bv0.x,bv0.y,bv0.z,bv0.w,bv1.x,bv1.y,bv1.z,bv1.w};
            #pragma unroll
            for (int i = 0; i < 8; ++i)
                #pragma unroll
                for (int j = 0; j < 8; ++j)
                    acc[i][j] += a[i] * b[j];
        }
    }

    float4 bb0 = *(const float4*)&bias[bn + tx*8];
    float4 bb1 = *(const float4*)&bias[bn + tx*8 + 4];
    float bb[8] = {bb0.x,bb0.y,bb0.z,bb0.w,bb1.x,bb1.y,bb1.z,bb1.w};
    #pragma unroll
    for (int i = 0; i < 8; ++i) {
        const int row = bm + ty*8 + i;
        float4 o0 = {acc[i][0]+bb[0], acc[i][1]+bb[1], acc[i][2]+bb[2], acc[i][3]+bb[3]};
        float4 o1 = {acc[i][4]+bb[4], acc[i][5]+bb[5], acc[i][6]+bb[6], acc[i][7]+bb[7]};
        *(float4*)&C[(size_t)row * N + bn + tx*8]     = o0;
        *(float4*)&C[(size_t)row * N + bn + tx*8 + 4] = o1;
    }
}

// ---------------------------------------------------------------------------
// Flash attention, f32. One block per (bh, 128-row q-tile). 256 threads,
// per-thread 8 q-rows x 4 cols. K/V tiles of 64 rows; online softmax.
// qkv layout per token: [h*192 + (q:0..63 | k:64..127 | v:128..191)]
// out layout: [token][h*64 + d]
// ---------------------------------------------------------------------------
__global__ __launch_bounds__(256) void attn_kernel(
    const float* __restrict__ qkv, float* __restrict__ out)
{
    __shared__ float Qs[64][132];  // [d][r], pre-scaled by 1/8
    __shared__ float Ks[64][68];   // [d][c]
    __shared__ float Vs[64][68];   // [kk][d]
    __shared__ float Ps[64][132];  // [kk][r]

    const int tid = threadIdx.x;
    const int tx  = tid & 15;      // col group (4 cols)
    const int ty  = tid >> 4;      // row group (8 rows)
    const int bh  = blockIdx.y;
    const int b   = bh >> 4;
    const int h   = bh & 15;
    const int q0  = blockIdx.x * 128;

    const float* base = qkv + (size_t)b * S_LEN * DQKV + h * 192;

    // ---- load Q tile (128 x 64), transposed + pre-scaled ----
    {
        const int lr   = tid & 127;
        const int doff = (tid >> 7) * 32;
        const float* qp = base + (size_t)(q0 + lr) * DQKV + doff;
        #pragma unroll
        for (int q = 0; q < 8; ++q) {
            float4 v = *(const float4*)(qp + 4*q);
            const int d = doff + 4*q;
            Qs[d+0][lr] = v.x * 0.125f;
            Qs[d+1][lr] = v.y * 0.125f;
            Qs[d+2][lr] = v.z * 0.125f;
            Qs[d+3][lr] = v.w * 0.125f;
        }
    }

    float m[8], l[8];
    float accO[8][4] = {};
    #pragma unroll
    for (int i = 0; i < 8; ++i) { m[i] = -1e30f; l[i] = 0.0f; }

    const int kr   = tid & 63;          // k/v row this thread loads
    const int koff = (tid >> 6) * 16;   // d-chunk

    for (int kt = 0; kt < S_LEN; kt += 64) {
        const float* kp = base + (size_t)(kt + kr) * DQKV + HDIM   + koff;
        const float* vp = base + (size_t)(kt + kr) * DQKV + 2*HDIM + koff;
        float4 kv[4], vv[4];
        #pragma unroll
        for (int q = 0; q < 4; ++q) {
            kv[q] = *(const float4*)(kp + 4*q);
            vv[q] = *(const float4*)(vp + 4*q);
        }
        __syncthreads();  // previous iteration's PV + P reads complete
        #pragma unroll
        for (int q = 0; q < 4; ++q) {
            const int d = koff + 4*q;
            Ks[d+0][kr] = kv[q].x; Ks[d+1][kr] = kv[q].y;
            Ks[d+2][kr] = kv[q].z; Ks[d+3][kr] = kv[q].w;
            *(float4*)&Vs[kr][koff + 4*q] = vv[q];
        }
        __syncthreads();

        // ---- S = (Q/8) K^T : per-thread 8x4 ----
        float s[8][4] = {};
        #pragma unroll 8
        for (int d = 0; d < 64; ++d) {
            float4 a0 = *(const float4*)&Qs[d][ty*8];
            float4 a1 = *(const float4*)&Qs[d][ty*8+4];
            float4 bv = *(const float4*)&Ks[d][tx*4];
            float a[8] = {a0.x,a0.y,a0.z,a0.w,a1.x,a1.y,a1.z,a1.w};
            float bq[4] = {bv.x,bv.y,bv.z,bv.w};
            #pragma unroll
            for (int i = 0; i < 8; ++i)
                #pragma unroll
                for (int j = 0; j < 4; ++j)
                    s[i][j] += a[i] * bq[j];
        }

        // ---- online softmax (row reduce across the 16 tx lanes) ----
        #pragma unroll
        for (int i = 0; i < 8; ++i) {
            float mx = fmaxf(fmaxf(s[i][0], s[i][1]), fmaxf(s[i][2], s[i][3]));
            mx = fmaxf(mx, __shfl_xor(mx, 1));
            mx = fmaxf(mx, __shfl_xor(mx, 2));
            mx = fmaxf(mx, __shfl_xor(mx, 4));
            mx = fmaxf(mx, __shfl_xor(mx, 8));
            const float mn   = fmaxf(m[i], mx);
            const float corr = __expf(m[i] - mn);
            m[i] = mn;
            float rs = 0.0f;
            #pragma unroll
            for (int j = 0; j < 4; ++j) {
                s[i][j] = __expf(s[i][j] - mn);
                rs += s[i][j];
            }
            rs += __shfl_xor(rs, 1);
            rs += __shfl_xor(rs, 2);
            rs += __shfl_xor(rs, 4);
            rs += __shfl_xor(rs, 8);
            l[i] = l[i] * corr + rs;
            #pragma unroll
            for (int j = 0; j < 4; ++j) accO[i][j] *= corr;
        }

        // ---- stage P transposed: Ps[col][row] ----
        #pragma unroll
        for (int j = 0; j < 4; ++j) {
            float4 p0 = {s[0][j], s[1][j], s[2][j], s[3][j]};
            float4 p1 = {s[4][j], s[5][j], s[6][j], s[7][j]};
            *(float4*)&Ps[tx*4+j][ty*8]   = p0;
            *(float4*)&Ps[tx*4+j][ty*8+4] = p1;
        }
        __syncthreads();

        // ---- O += P V ----
        #pragma unroll 8
        for (int kk = 0; kk < 64; ++kk) {
            float4 a0 = *(const float4*)&Ps[kk][ty*8];
            float4 a1 = *(const float4*)&Ps[kk][ty*8+4];
            float4 bv = *(const float4*)&Vs[kk][tx*4];
            float a[8] = {a0.x,a0.y,a0.z,a0.w,a1.x,a1.y,a1.z,a1.w};
            float bq[4] = {bv.x,bv.y,bv.z,bv.w};
            #pragma unroll
            for (int i = 0; i < 8; ++i)
                #pragma unroll
                for (int j = 0; j < 4; ++j)
                    accO[i][j] += a[i] * bq[j];
        }
    }

    // ---- epilogue: normalize + write (b, s, h*64+d) ----
    #pragma unroll
    for (int i = 0; i < 8; ++i) {
        const float inv = 1.0f / l[i];
        const int row = q0 + ty*8 + i;
        float4 o = {accO[i][0]*inv, accO[i][1]*inv, accO[i][2]*inv, accO[i][3]*inv};
        *(float4*)&out[(size_t)(b * S_LEN + row) * D_MODEL + h * HDIM + tx*4] = o;
    }
}

// ---------------------------------------------------------------------------
extern "C" void kernel_launch(void* const* d_in, const int* in_sizes, int n_in,
                              void* d_out, int out_size, void* d_ws, size_t ws_size,
                              hipStream_t stream)
{
    const float* x     = (const float*)d_in[0];
    const float* w_qkv = (const float*)d_in[1];
    const float* b_qkv = (const float*)d_in[2];
    const float* w_out = (const float*)d_in[3];
    const float* b_out = (const float*)d_in[4];
    float* out = (float*)d_out;

    float* qkv  = (float*)d_ws;                       // 4096 x 3072 f32 = 50.3 MB
    float* attn = qkv + (size_t)4096 * DQKV;          // 4096 x 1024 f32 = 16.8 MB

    const int M = NBATCH * S_LEN;  // 4096

    dim3 blk(256);
    // QKV projection: [4096,1024] @ [3072,1024]^T + b
    gemm_bias_kernel<<<dim3(DQKV/128, M/128), blk, 0, stream>>>(
        x, w_qkv, b_qkv, qkv, M, DQKV, D_MODEL);
    // attention: grid = (q-tiles, B*H)
    attn_kernel<<<dim3(S_LEN/128, NBATCH*NHEADS), blk, 0, stream>>>(qkv, attn);
    // output projection: [4096,1024] @ [1024,1024]^T + b
    gemm_bias_kernel<<<dim3(D_MODEL/128, M/128), blk, 0, stream>>>(
        attn, w_out, b_out, out, M, D_MODEL, D_MODEL);
}

// Round 2
// 712.770 us; speedup vs baseline: 1.5383x; 1.5383x over previous
//
#include <hip/hip_runtime.h>
#include <hip/hip_bf16.h>

#define D_MODEL 1024
#define S_LEN   2048
#define NBATCH  2
#define NHEADS  16
#define HDIM    64
#define DQKV    3072   // 3 * D_MODEL

typedef short bf16x8 __attribute__((ext_vector_type(8)));
typedef float f32x4  __attribute__((ext_vector_type(4)));

// ---------------------------------------------------------------------------
// bf16 split helpers: x = hi + lo, each bf16 (RNE). hi+lo ~ 16-bit mantissa.
// ---------------------------------------------------------------------------
__device__ __forceinline__ unsigned short bf16_rne(float f) {
    unsigned u = __float_as_uint(f);
    return (unsigned short)((u + 0x7FFFu + ((u >> 16) & 1u)) >> 16);
}
__device__ __forceinline__ void bf16_split(float f, unsigned short& h, unsigned short& l) {
    h = bf16_rne(f);
    float hf = __uint_as_float(((unsigned)h) << 16);
    l = bf16_rne(f - hf);
}

// ---------------------------------------------------------------------------
// Elementwise: f32[n4*4] -> hi bf16 plane, lo bf16 plane
// ---------------------------------------------------------------------------
__global__ __launch_bounds__(256) void split_f32_bf16(
    const float* __restrict__ in, unsigned short* __restrict__ hi,
    unsigned short* __restrict__ lo, int n4)
{
    int i = blockIdx.x * blockDim.x + threadIdx.x;
    const int stride = gridDim.x * blockDim.x;
    for (; i < n4; i += stride) {
        float4 v = ((const float4*)in)[i];
        float f[4] = {v.x, v.y, v.z, v.w};
        unsigned short hh[4], ll[4];
        #pragma unroll
        for (int j = 0; j < 4; ++j) bf16_split(f[j], hh[j], ll[j]);
        ((ushort4*)hi)[i] = make_ushort4(hh[0], hh[1], hh[2], hh[3]);
        ((ushort4*)lo)[i] = make_ushort4(ll[0], ll[1], ll[2], ll[3]);
    }
}

// ---------------------------------------------------------------------------
// global -> LDS direct (16B per lane). LDS dst is wave-uniform base; HW adds
// lane*16. Global src is per-lane.
// ---------------------------------------------------------------------------
__device__ __forceinline__ void gld_lds16(const unsigned short* g, unsigned short* l) {
    __builtin_amdgcn_global_load_lds(
        (const __attribute__((address_space(1))) unsigned int*)g,
        (__attribute__((address_space(3))) unsigned int*)l, 16, 0, 0);
}

// ---------------------------------------------------------------------------
// C[M][N] = (Ah+Al)[M][K] * (Bh+Bl)[N][K]^T + bias[N]  via split-bf16 MFMA.
// 128x128 tile, BK=32, 4 waves; wave quadrant 64x64 = 4x4 frags of 16x16.
// 3 MFMA products per frag pair (hh, hl, lh); al*bl dropped (~2^-18).
// ---------------------------------------------------------------------------
__global__ __launch_bounds__(256) void gemm_mfma_split(
    const unsigned short* __restrict__ Ah, const unsigned short* __restrict__ Al,
    const unsigned short* __restrict__ Bh, const unsigned short* __restrict__ Bl,
    const float* __restrict__ bias, float* __restrict__ C,
    int M, int N, int K)
{
    __shared__ unsigned short sAh[128 * 32];
    __shared__ unsigned short sAl[128 * 32];
    __shared__ unsigned short sBh[128 * 32];
    __shared__ unsigned short sBl[128 * 32];

    const int tid  = threadIdx.x;
    const int lane = tid & 63;
    const int wid  = tid >> 6;
    const int bm = blockIdx.y * 128, bn = blockIdx.x * 128;
    const int wr = (wid >> 1) * 64, wc = (wid & 1) * 64;

    // each wave stages one 128x32 bf16 plane per K-step (8 x 1KB chunks)
    const unsigned short* gsrc = (wid == 0) ? Ah : (wid == 1) ? Al : (wid == 2) ? Bh : Bl;
    unsigned short* ldst = (wid == 0) ? sAh : (wid == 1) ? sAl : (wid == 2) ? sBh : sBl;
    const int brow = (wid < 2) ? bm : bn;
    const size_t rowbase = (size_t)(brow + (lane >> 2)) * K + (lane & 3) * 8;

    f32x4 acc[4][4];
    #pragma unroll
    for (int m = 0; m < 4; ++m)
        #pragma unroll
        for (int n = 0; n < 4; ++n)
            acc[m][n] = f32x4{0.f, 0.f, 0.f, 0.f};

    const int frA = (wr + (lane & 15)) * 32 + (lane >> 4) * 8;  // ushort index
    const int frB = (wc + (lane & 15)) * 32 + (lane >> 4) * 8;

    for (int k0 = 0; k0 < K; k0 += 32) {
        __syncthreads();   // previous iteration's fragments consumed
        const unsigned short* g = gsrc + rowbase + k0;
        #pragma unroll
        for (int c = 0; c < 8; ++c)
            gld_lds16(g + (size_t)c * 16 * K, ldst + c * 512);
        __syncthreads();   // staging complete (vmcnt drained at barrier)

        bf16x8 ah[4], al[4], bh[4], bl[4];
        #pragma unroll
        for (int m = 0; m < 4; ++m) {
            ah[m] = *(const bf16x8*)&sAh[frA + m * 16 * 32];
            al[m] = *(const bf16x8*)&sAl[frA + m * 16 * 32];
        }
        #pragma unroll
        for (int n = 0; n < 4; ++n) {
            bh[n] = *(const bf16x8*)&sBh[frB + n * 16 * 32];
            bl[n] = *(const bf16x8*)&sBl[frB + n * 16 * 32];
        }
        #pragma unroll
        for (int m = 0; m < 4; ++m)
            #pragma unroll
            for (int n = 0; n < 4; ++n) {
                acc[m][n] = __builtin_amdgcn_mfma_f32_16x16x32_bf16(ah[m], bh[n], acc[m][n], 0, 0, 0);
                acc[m][n] = __builtin_amdgcn_mfma_f32_16x16x32_bf16(ah[m], bl[n], acc[m][n], 0, 0, 0);
                acc[m][n] = __builtin_amdgcn_mfma_f32_16x16x32_bf16(al[m], bh[n], acc[m][n], 0, 0, 0);
            }
    }

    // epilogue: D layout col=lane&15, row=(lane>>4)*4+j  [verified m89/m91]
    #pragma unroll
    for (int n = 0; n < 4; ++n) {
        const int col = bn + wc + n * 16 + (lane & 15);
        const float bv = bias[col];
        #pragma unroll
        for (int m = 0; m < 4; ++m) {
            const int row0 = bm + wr + m * 16 + (lane >> 4) * 4;
            #pragma unroll
            for (int j = 0; j < 4; ++j)
                C[(size_t)(row0 + j) * N + col] = acc[m][n][j] + bv;
        }
    }
}

// ---------------------------------------------------------------------------
// Flash attention, f32 VALU. q-tile 64, kv-tile 64, 256 thr, 4x4 per thread.
// LDS = 4 x 16KB = 64KB -> 2 blocks/CU. XOR swizzle on Vs/Ps transposed
// writes (bank-conflict fix). Output written as bf16 hi/lo planes for the
// MFMA out-projection.
// ---------------------------------------------------------------------------
__global__ __launch_bounds__(256) void attn_kernel(
    const float* __restrict__ qkv,
    unsigned short* __restrict__ oh, unsigned short* __restrict__ ol)
{
    __shared__ float Qs[64][64];   // [d][qrow], pre-scaled by 1/8
    __shared__ float Ks[64][64];   // [d][kvcol]
    __shared__ float Vs[64][64];   // [kv][d], cols XOR-swizzled by kv row
    __shared__ float Ps[64][64];   // [kv][qrow], cols XOR-swizzled by kv row

    const int tid = threadIdx.x;
    const int tx  = tid & 15;      // kv-col group (4 cols)
    const int ty  = tid >> 4;      // q-row group (4 rows)
    const int bh  = blockIdx.y;
    const int b   = bh >> 4;
    const int h   = bh & 15;
    const int q0  = blockIdx.x * 64;

    const float* base = qkv + (size_t)b * S_LEN * DQKV + h * 192;

    // ---- load Q tile (64 x 64), transposed + pre-scaled ----
    {
        const int lr   = tid & 63;
        const int doff = (tid >> 6) * 16;
        const float* qp = base + (size_t)(q0 + lr) * DQKV + doff;
        #pragma unroll
        for (int q = 0; q < 4; ++q) {
            float4 v = *(const float4*)(qp + 4 * q);
            const int d = doff + 4 * q;
            Qs[d + 0][lr] = v.x * 0.125f;
            Qs[d + 1][lr] = v.y * 0.125f;
            Qs[d + 2][lr] = v.z * 0.125f;
            Qs[d + 3][lr] = v.w * 0.125f;
        }
    }

    float m[4], l[4];
    float accO[4][4] = {};
    #pragma unroll
    for (int i = 0; i < 4; ++i) { m[i] = -1e30f; l[i] = 0.0f; }

    const int kr   = tid & 63;
    const int koff = (tid >> 6) * 16;

    for (int kt = 0; kt < S_LEN; kt += 64) {
        const float* kp = base + (size_t)(kt + kr) * DQKV + HDIM     + koff;
        const float* vp = base + (size_t)(kt + kr) * DQKV + 2 * HDIM + koff;
        float4 kv[4], vv[4];
        #pragma unroll
        for (int q = 0; q < 4; ++q) {
            kv[q] = *(const float4*)(kp + 4 * q);
            vv[q] = *(const float4*)(vp + 4 * q);
        }
        __syncthreads();  // prev PV reads done (also covers Q-load on iter 0)
        #pragma unroll
        for (int q = 0; q < 4; ++q) {
            const int d = koff + 4 * q;
            Ks[d + 0][kr] = kv[q].x; Ks[d + 1][kr] = kv[q].y;
            Ks[d + 2][kr] = kv[q].z; Ks[d + 3][kr] = kv[q].w;
            *(float4*)&Vs[kr][(koff + 4 * q) ^ (4 * (kr & 7))] = vv[q];
        }
        __syncthreads();

        // ---- S = (Q/8) K^T : per-thread 4x4 ----
        float s[4][4] = {};
        #pragma unroll 8
        for (int d = 0; d < 64; ++d) {
            float4 a4 = *(const float4*)&Qs[d][ty * 4];
            float4 b4 = *(const float4*)&Ks[d][tx * 4];
            float a[4] = {a4.x, a4.y, a4.z, a4.w};
            float bq[4] = {b4.x, b4.y, b4.z, b4.w};
            #pragma unroll
            for (int i = 0; i < 4; ++i)
                #pragma unroll
                for (int j = 0; j < 4; ++j)
                    s[i][j] += a[i] * bq[j];
        }

        // ---- online softmax (row reduce across 16 tx lanes) ----
        #pragma unroll
        for (int i = 0; i < 4; ++i) {
            float mx = fmaxf(fmaxf(s[i][0], s[i][1]), fmaxf(s[i][2], s[i][3]));
            mx = fmaxf(mx, __shfl_xor(mx, 1));
            mx = fmaxf(mx, __shfl_xor(mx, 2));
            mx = fmaxf(mx, __shfl_xor(mx, 4));
            mx = fmaxf(mx, __shfl_xor(mx, 8));
            const float mn   = fmaxf(m[i], mx);
            const float corr = __expf(m[i] - mn);
            m[i] = mn;
            float rs = 0.0f;
            #pragma unroll
            for (int j = 0; j < 4; ++j) {
                s[i][j] = __expf(s[i][j] - mn);
                rs += s[i][j];
            }
            rs += __shfl_xor(rs, 1);
            rs += __shfl_xor(rs, 2);
            rs += __shfl_xor(rs, 4);
            rs += __shfl_xor(rs, 8);
            l[i] = l[i] * corr + rs;
            #pragma unroll
            for (int j = 0; j < 4; ++j) accO[i][j] *= corr;
        }

        // ---- stage P transposed (swizzled): Ps[kv][qrow] ----
        #pragma unroll
        for (int j = 0; j < 4; ++j) {
            float4 p = {s[0][j], s[1][j], s[2][j], s[3][j]};
            *(float4*)&Ps[tx * 4 + j][(ty * 4) ^ (4 * (tx & 7))] = p;
        }
        __syncthreads();

        // ---- O += P V ----
        #pragma unroll 8
        for (int kk = 0; kk < 64; ++kk) {
            float4 p4 = *(const float4*)&Ps[kk][(ty * 4) ^ (4 * ((kk >> 2) & 7))];
            float4 v4 = *(const float4*)&Vs[kk][(tx * 4) ^ (4 * (kk & 7))];
            float a[4] = {p4.x, p4.y, p4.z, p4.w};
            float bq[4] = {v4.x, v4.y, v4.z, v4.w};
            #pragma unroll
            for (int i = 0; i < 4; ++i)
                #pragma unroll
                for (int j = 0; j < 4; ++j)
                    accO[i][j] += a[i] * bq[j];
        }
    }

    // ---- epilogue: normalize + split-bf16 write ----
    #pragma unroll
    for (int i = 0; i < 4; ++i) {
        const float inv = 1.0f / l[i];
        const int row = q0 + ty * 4 + i;
        const size_t idx = (size_t)(b * S_LEN + row) * D_MODEL + h * HDIM + tx * 4;
        unsigned short hh[4], ll[4];
        #pragma unroll
        for (int j = 0; j < 4; ++j) bf16_split(accO[i][j] * inv, hh[j], ll[j]);
        *(ushort4*)&oh[idx] = make_ushort4(hh[0], hh[1], hh[2], hh[3]);
        *(ushort4*)&ol[idx] = make_ushort4(ll[0], ll[1], ll[2], ll[3]);
    }
}

// ---------------------------------------------------------------------------
extern "C" void kernel_launch(void* const* d_in, const int* in_sizes, int n_in,
                              void* d_out, int out_size, void* d_ws, size_t ws_size,
                              hipStream_t stream)
{
    const float* x     = (const float*)d_in[0];
    const float* w_qkv = (const float*)d_in[1];
    const float* b_qkv = (const float*)d_in[2];
    const float* w_out = (const float*)d_in[3];
    const float* b_out = (const float*)d_in[4];
    float* out = (float*)d_out;

    const int M = NBATCH * S_LEN;  // 4096

    // Workspace budget: 67.1 MB proven. Layout:
    //   R1 = qkv f32 (50.33 MB), later reused for w_out hi/lo planes
    //   R2 = x hi/lo planes (16.78 MB), later reused for attn-out hi/lo
    // d_out (16.78 MB) doubles as scratch for w_qkv hi/lo planes (12.58 MB),
    // dead before gemm2 writes the real output there.
    char* ws = (char*)d_ws;
    float* qkvf = (float*)ws;                                    // 50331648 B
    unsigned short* xh = (unsigned short*)(ws + (size_t)50331648);
    unsigned short* xl = xh + (size_t)M * D_MODEL;               // R2
    unsigned short* wqh = (unsigned short*)d_out;
    unsigned short* wql = wqh + (size_t)DQKV * D_MODEL;
    unsigned short* aoh = xh;                                    // alias (after gemm1)
    unsigned short* aol = xl;
    unsigned short* woh = (unsigned short*)ws;                   // alias (after attn)
    unsigned short* wol = woh + (size_t)D_MODEL * D_MODEL;

    dim3 blk(256);
    split_f32_bf16<<<1024, blk, 0, stream>>>(x, xh, xl, M * D_MODEL / 4);
    split_f32_bf16<<<1024, blk, 0, stream>>>(w_qkv, wqh, wql, DQKV * D_MODEL / 4);

    gemm_mfma_split<<<dim3(DQKV / 128, M / 128), blk, 0, stream>>>(
        xh, xl, wqh, wql, b_qkv, qkvf, M, DQKV, D_MODEL);

    attn_kernel<<<dim3(S_LEN / 64, NBATCH * NHEADS), blk, 0, stream>>>(qkvf, aoh, aol);

    split_f32_bf16<<<512, blk, 0, stream>>>(w_out, woh, wol, D_MODEL * D_MODEL / 4);

    gemm_mfma_split<<<dim3(D_MODEL / 128, M / 128), blk, 0, stream>>>(
        aoh, aol, woh, wol, b_out, out, M, D_MODEL, D_MODEL);
}

// Round 3
// 291.029 us; speedup vs baseline: 3.7675x; 2.4491x over previous
//
#include <hip/hip_runtime.h>
#include <hip/hip_bf16.h>

#define D_MODEL 1024
#define S_LEN   2048
#define NBATCH  2
#define NHEADS  16
#define HDIM    64
#define DQKV    3072   // 3 * D_MODEL

typedef short bf16x8 __attribute__((ext_vector_type(8)));
typedef float f32x4  __attribute__((ext_vector_type(4)));
typedef float f32x16 __attribute__((ext_vector_type(16)));
typedef unsigned int u32;

// ---------------------------------------------------------------------------
// bf16 split helpers: x = hi + lo, each bf16 (RNE).
// ---------------------------------------------------------------------------
__device__ __forceinline__ unsigned short bf16_rne(float f) {
    unsigned u = __float_as_uint(f);
    return (unsigned short)((u + 0x7FFFu + ((u >> 16) & 1u)) >> 16);
}
__device__ __forceinline__ void bf16_split(float f, unsigned short& h, unsigned short& l) {
    h = bf16_rne(f);
    float hf = __uint_as_float(((unsigned)h) << 16);
    l = bf16_rne(f - hf);
}

__global__ __launch_bounds__(256) void split_f32_bf16(
    const float* __restrict__ in, unsigned short* __restrict__ hi,
    unsigned short* __restrict__ lo, int n4)
{
    int i = blockIdx.x * blockDim.x + threadIdx.x;
    const int stride = gridDim.x * blockDim.x;
    for (; i < n4; i += stride) {
        float4 v = ((const float4*)in)[i];
        float f[4] = {v.x, v.y, v.z, v.w};
        unsigned short hh[4], ll[4];
        #pragma unroll
        for (int j = 0; j < 4; ++j) bf16_split(f[j], hh[j], ll[j]);
        ((ushort4*)hi)[i] = make_ushort4(hh[0], hh[1], hh[2], hh[3]);
        ((ushort4*)lo)[i] = make_ushort4(ll[0], ll[1], ll[2], ll[3]);
    }
}

__device__ __forceinline__ void gld_lds16(const unsigned short* g, unsigned short* l) {
    __builtin_amdgcn_global_load_lds(
        (const __attribute__((address_space(1))) unsigned int*)g,
        (__attribute__((address_space(3))) unsigned int*)l, 16, 0, 0);
}

// Swizzled LDS fragment read: tile rows of 64 ushort (128B), byte ^= (row&7)<<4
__device__ __forceinline__ bf16x8 lds_frag(const unsigned short* base, int row, int e8) {
    int byte = (row << 7) + (e8 << 4);
    byte ^= (row & 7) << 4;
    return *(const bf16x8*)((const char*)base + byte);
}

// ---------------------------------------------------------------------------
// Generic split-bf16 MFMA GEMM (used for out-projection).
// C[M][N] = (Ah+Al)(Bh+Bl)^T + bias. 128x128 tile, BK=32, 4 waves.
// ---------------------------------------------------------------------------
__global__ __launch_bounds__(256) void gemm_mfma_split(
    const unsigned short* __restrict__ Ah, const unsigned short* __restrict__ Al,
    const unsigned short* __restrict__ Bh, const unsigned short* __restrict__ Bl,
    const float* __restrict__ bias, float* __restrict__ C,
    int M, int N, int K)
{
    __shared__ unsigned short sAh[128 * 32];
    __shared__ unsigned short sAl[128 * 32];
    __shared__ unsigned short sBh[128 * 32];
    __shared__ unsigned short sBl[128 * 32];

    const int tid  = threadIdx.x;
    const int lane = tid & 63;
    const int wid  = tid >> 6;
    const int bm = blockIdx.y * 128, bn = blockIdx.x * 128;
    const int wr = (wid >> 1) * 64, wc = (wid & 1) * 64;

    const unsigned short* gsrc = (wid == 0) ? Ah : (wid == 1) ? Al : (wid == 2) ? Bh : Bl;
    unsigned short* ldst = (wid == 0) ? sAh : (wid == 1) ? sAl : (wid == 2) ? sBh : sBl;
    const int brow = (wid < 2) ? bm : bn;
    const size_t rowbase = (size_t)(brow + (lane >> 2)) * K + (lane & 3) * 8;

    f32x4 acc[4][4];
    #pragma unroll
    for (int m = 0; m < 4; ++m)
        #pragma unroll
        for (int n = 0; n < 4; ++n)
            acc[m][n] = f32x4{0.f, 0.f, 0.f, 0.f};

    const int frA = (wr + (lane & 15)) * 32 + (lane >> 4) * 8;
    const int frB = (wc + (lane & 15)) * 32 + (lane >> 4) * 8;

    for (int k0 = 0; k0 < K; k0 += 32) {
        __syncthreads();
        const unsigned short* g = gsrc + rowbase + k0;
        #pragma unroll
        for (int c = 0; c < 8; ++c)
            gld_lds16(g + (size_t)c * 16 * K, ldst + c * 512);
        __syncthreads();

        bf16x8 ah[4], al[4], bh[4], bl[4];
        #pragma unroll
        for (int m = 0; m < 4; ++m) {
            ah[m] = *(const bf16x8*)&sAh[frA + m * 16 * 32];
            al[m] = *(const bf16x8*)&sAl[frA + m * 16 * 32];
        }
        #pragma unroll
        for (int n = 0; n < 4; ++n) {
            bh[n] = *(const bf16x8*)&sBh[frB + n * 16 * 32];
            bl[n] = *(const bf16x8*)&sBl[frB + n * 16 * 32];
        }
        #pragma unroll
        for (int m = 0; m < 4; ++m)
            #pragma unroll
            for (int n = 0; n < 4; ++n) {
                acc[m][n] = __builtin_amdgcn_mfma_f32_16x16x32_bf16(ah[m], bh[n], acc[m][n], 0, 0, 0);
                acc[m][n] = __builtin_amdgcn_mfma_f32_16x16x32_bf16(ah[m], bl[n], acc[m][n], 0, 0, 0);
                acc[m][n] = __builtin_amdgcn_mfma_f32_16x16x32_bf16(al[m], bh[n], acc[m][n], 0, 0, 0);
            }
    }

    #pragma unroll
    for (int n = 0; n < 4; ++n) {
        const int col = bn + wc + n * 16 + (lane & 15);
        const float bv = bias[col];
        #pragma unroll
        for (int m = 0; m < 4; ++m) {
            const int row0 = bm + wr + m * 16 + (lane >> 4) * 4;
            #pragma unroll
            for (int j = 0; j < 4; ++j)
                C[(size_t)(row0 + j) * N + col] = acc[m][n][j] + bv;
        }
    }
}

// ---------------------------------------------------------------------------
// QKV GEMM: same core, epilogue scatters into bf16 hi/lo planes:
//   Q plane [b,h,s,d] (pre-scaled by 1/8), K plane [b,h,s,d], Vt plane [b,h,d,s]
// ---------------------------------------------------------------------------
__global__ __launch_bounds__(256) void gemm_mfma_qkv(
    const unsigned short* __restrict__ Ah, const unsigned short* __restrict__ Al,
    const unsigned short* __restrict__ Bh, const unsigned short* __restrict__ Bl,
    const float* __restrict__ bias,
    unsigned short* __restrict__ Qh, unsigned short* __restrict__ Ql,
    unsigned short* __restrict__ Kh, unsigned short* __restrict__ Kl,
    unsigned short* __restrict__ Vth, unsigned short* __restrict__ Vtl,
    int M, int N, int K)
{
    __shared__ unsigned short sAh[128 * 32];
    __shared__ unsigned short sAl[128 * 32];
    __shared__ unsigned short sBh[128 * 32];
    __shared__ unsigned short sBl[128 * 32];

    const int tid  = threadIdx.x;
    const int lane = tid & 63;
    const int wid  = tid >> 6;
    const int bm = blockIdx.y * 128, bn = blockIdx.x * 128;
    const int wr = (wid >> 1) * 64, wc = (wid & 1) * 64;

    const unsigned short* gsrc = (wid == 0) ? Ah : (wid == 1) ? Al : (wid == 2) ? Bh : Bl;
    unsigned short* ldst = (wid == 0) ? sAh : (wid == 1) ? sAl : (wid == 2) ? sBh : sBl;
    const int brow = (wid < 2) ? bm : bn;
    const size_t rowbase = (size_t)(brow + (lane >> 2)) * K + (lane & 3) * 8;

    f32x4 acc[4][4];
    #pragma unroll
    for (int m = 0; m < 4; ++m)
        #pragma unroll
        for (int n = 0; n < 4; ++n)
            acc[m][n] = f32x4{0.f, 0.f, 0.f, 0.f};

    const int frA = (wr + (lane & 15)) * 32 + (lane >> 4) * 8;
    const int frB = (wc + (lane & 15)) * 32 + (lane >> 4) * 8;

    for (int k0 = 0; k0 < K; k0 += 32) {
        __syncthreads();
        const unsigned short* g = gsrc + rowbase + k0;
        #pragma unroll
        for (int c = 0; c < 8; ++c)
            gld_lds16(g + (size_t)c * 16 * K, ldst + c * 512);
        __syncthreads();

        bf16x8 ah[4], al[4], bh[4], bl[4];
        #pragma unroll
        for (int m = 0; m < 4; ++m) {
            ah[m] = *(const bf16x8*)&sAh[frA + m * 16 * 32];
            al[m] = *(const bf16x8*)&sAl[frA + m * 16 * 32];
        }
        #pragma unroll
        for (int n = 0; n < 4; ++n) {
            bh[n] = *(const bf16x8*)&sBh[frB + n * 16 * 32];
            bl[n] = *(const bf16x8*)&sBl[frB + n * 16 * 32];
        }
        #pragma unroll
        for (int m = 0; m < 4; ++m)
            #pragma unroll
            for (int n = 0; n < 4; ++n) {
                acc[m][n] = __builtin_amdgcn_mfma_f32_16x16x32_bf16(ah[m], bh[n], acc[m][n], 0, 0, 0);
                acc[m][n] = __builtin_amdgcn_mfma_f32_16x16x32_bf16(ah[m], bl[n], acc[m][n], 0, 0, 0);
                acc[m][n] = __builtin_amdgcn_mfma_f32_16x16x32_bf16(al[m], bh[n], acc[m][n], 0, 0, 0);
            }
    }

    #pragma unroll
    for (int n = 0; n < 4; ++n) {
        const int col = bn + wc + n * 16 + (lane & 15);
        const unsigned head = (unsigned)col / 192u;
        const int c = col - (int)head * 192;
        const int cls = c >> 6;                    // 0=q 1=k 2=v (uniform per n)
        const float bv = bias[col];
        #pragma unroll
        for (int m = 0; m < 4; ++m) {
            const int row0 = bm + wr + m * 16 + (lane >> 4) * 4;
            #pragma unroll
            for (int j = 0; j < 4; ++j) {
                const int row = row0 + j;
                const int bb = row >> 11, ss = row & 2047;
                float val = acc[m][n][j] + bv;
                if (cls == 0) val *= 0.125f;       // fold 1/sqrt(hd) into Q
                unsigned short vh_, vl_;
                bf16_split(val, vh_, vl_);
                if (cls == 2) {
                    const size_t idx = ((size_t)(bb * NHEADS + head) * HDIM + (c - 128)) * S_LEN + ss;
                    Vth[idx] = vh_; Vtl[idx] = vl_;
                } else {
                    const size_t idx = ((size_t)(bb * NHEADS + head) * S_LEN + ss) * HDIM + (c & 63);
                    if (cls == 0) { Qh[idx] = vh_; Ql[idx] = vl_; }
                    else          { Kh[idx] = vh_; Kl[idx] = vl_; }
                }
            }
        }
    }
}

// ---------------------------------------------------------------------------
// MFMA flash attention. Grid: 512 blocks (16 q-tiles x 32 bh), 4 waves.
// QBLK=128 (32 q-rows/wave), KVBLK=64. Swapped QK^T (S^T = K.Q^T) so each
// lane owns one q-column; P^T converts in-register to PV's B-operand.
// K/V tiles staged via global_load_lds with pre-swizzled sources.
// ---------------------------------------------------------------------------
__global__ __launch_bounds__(256) void attn_mfma_kernel(
    const unsigned short* __restrict__ Qh, const unsigned short* __restrict__ Ql,
    const unsigned short* __restrict__ Kh, const unsigned short* __restrict__ Kl,
    const unsigned short* __restrict__ Vth, const unsigned short* __restrict__ Vtl,
    unsigned short* __restrict__ oh, unsigned short* __restrict__ ol)
{
    __shared__ unsigned short sKh[64 * 64];
    __shared__ unsigned short sKl[64 * 64];
    __shared__ unsigned short sVh[64 * 64];
    __shared__ unsigned short sVl[64 * 64];

    const int tid  = threadIdx.x;
    const int lane = tid & 63;
    const int wid  = tid >> 6;
    const int h    = lane >> 5;        // k-octet half
    const int qcol = lane & 31;

    // XCD-chunked remap: 512 blocks, XCD = bid%8 gets a contiguous 64-chunk
    const int bid = blockIdx.x;
    const int lb  = (bid & 7) * 64 + (bid >> 3);
    const int qt  = lb & 15;
    const int bh  = lb >> 4;

    const int q0 = qt * 128 + wid * 32;

    // ---- Q fragments in registers (pre-scaled at GEMM1) ----
    bf16x8 qfh[4], qfl[4];
    {
        const unsigned short* qrh = Qh + ((size_t)bh * S_LEN + q0 + qcol) * HDIM + h * 8;
        const unsigned short* qrl = Ql + ((size_t)bh * S_LEN + q0 + qcol) * HDIM + h * 8;
        #pragma unroll
        for (int ks = 0; ks < 4; ++ks) {
            qfh[ks] = *(const bf16x8*)(qrh + ks * 16);
            qfl[ks] = *(const bf16x8*)(qrl + ks * 16);
        }
    }

    // ---- staging setup: wave w stages plane w; inverse-swizzled source ----
    const unsigned short* gK = (wid == 0) ? Kh : Kl;
    const unsigned short* gV = (wid == 2) ? Vth : Vtl;
    unsigned short* lb_ = (wid == 0) ? sKh : (wid == 1) ? sKl : (wid == 2) ? sVh : sVl;
    const int r8   = lane >> 3;                      // row within 8-row chunk
    const int colb = ((lane & 7) ^ r8) << 3;         // inverse-swizzled col (elements)

    float m_run = -1e30f, l_run = 0.0f;
    f32x16 accO[2];
    #pragma unroll
    for (int m = 0; m < 2; ++m)
        #pragma unroll
        for (int r = 0; r < 16; ++r) accO[m][r] = 0.0f;

    for (int kt = 0; kt < S_LEN; kt += 64) {
        __syncthreads();   // previous tile's LDS reads done
        if (wid < 2) {
            const unsigned short* g = gK + ((size_t)bh * S_LEN + kt + r8) * HDIM + colb;
            #pragma unroll
            for (int c = 0; c < 8; ++c)
                gld_lds16(g + (size_t)c * 8 * HDIM, lb_ + c * 512);
        } else {
            const unsigned short* g = gV + ((size_t)bh * HDIM + r8) * S_LEN + kt + colb;
            #pragma unroll
            for (int c = 0; c < 8; ++c)
                gld_lds16(g + (size_t)c * 8 * S_LEN, lb_ + c * 512);
        }
        __syncthreads();   // staging complete (vmcnt drained at barrier)

        // ---- S^T = K . Q^T : accS[mm] is 32kv x 32q, lane owns q=qcol ----
        f32x16 accS[2];
        #pragma unroll
        for (int mm = 0; mm < 2; ++mm)
            #pragma unroll
            for (int r = 0; r < 16; ++r) accS[mm][r] = 0.0f;

        #pragma unroll
        for (int ks = 0; ks < 4; ++ks) {
            const int e8 = ks * 2 + h;
            #pragma unroll
            for (int mm = 0; mm < 2; ++mm) {
                bf16x8 akh = lds_frag(sKh, mm * 32 + qcol, e8);
                bf16x8 akl = lds_frag(sKl, mm * 32 + qcol, e8);
                accS[mm] = __builtin_amdgcn_mfma_f32_32x32x16_bf16(akh, qfh[ks], accS[mm], 0, 0, 0);
                accS[mm] = __builtin_amdgcn_mfma_f32_32x32x16_bf16(akh, qfl[ks], accS[mm], 0, 0, 0);
                accS[mm] = __builtin_amdgcn_mfma_f32_32x32x16_bf16(akl, qfh[ks], accS[mm], 0, 0, 0);
            }
        }

        // ---- online softmax: lane-local over 32 regs + one shfl_xor(32) ----
        float p[32];
        #pragma unroll
        for (int mm = 0; mm < 2; ++mm)
            #pragma unroll
            for (int r = 0; r < 16; ++r) p[mm * 16 + r] = accS[mm][r];

        float mx = p[0];
        #pragma unroll
        for (int i = 1; i < 32; ++i) mx = fmaxf(mx, p[i]);
        mx = fmaxf(mx, __shfl_xor(mx, 32));
        const float mnew = fmaxf(m_run, mx);
        const float corr = __expf(m_run - mnew);
        m_run = mnew;
        float rs = 0.0f;
        #pragma unroll
        for (int i = 0; i < 32; ++i) { p[i] = __expf(p[i] - mnew); rs += p[i]; }
        rs += __shfl_xor(rs, 32);
        l_run = l_run * corr + rs;
        #pragma unroll
        for (int m = 0; m < 2; ++m)
            #pragma unroll
            for (int r = 0; r < 16; ++r) accO[m][r] *= corr;

        // ---- P^T -> bf16 hi/lo B-fragments (cvt_pk + shfl_xor(32)) + PV ----
        const bool hib = (h != 0);
        #pragma unroll
        for (int mm = 0; mm < 2; ++mm) {
            u32 wh_[8], wl_[8], sh_[8], sl_[8];
            #pragma unroll
            for (int i = 0; i < 8; ++i) {
                const float pe = p[mm * 16 + 2 * i], po = p[mm * 16 + 2 * i + 1];
                u32 a_;
                asm("v_cvt_pk_bf16_f32 %0, %1, %2" : "=v"(a_) : "v"(pe), "v"(po));
                const float he = __uint_as_float(a_ << 16);
                const float ho = __uint_as_float(a_ & 0xffff0000u);
                u32 b_;
                asm("v_cvt_pk_bf16_f32 %0, %1, %2" : "=v"(b_) : "v"(pe - he), "v"(po - ho));
                wh_[i] = a_; wl_[i] = b_;
            }
            #pragma unroll
            for (int i = 0; i < 8; ++i) {
                sh_[i] = __shfl_xor(wh_[i], 32);
                sl_[i] = __shfl_xor(wl_[i], 32);
            }
            #pragma unroll
            for (int cc = 0; cc < 2; ++cc) {
                const int b0 = cc * 4;
                union { u32 w[4]; bf16x8 v; } uh, ul;
                uh.w[0] = hib ? sh_[b0 + 2] : wh_[b0 + 0];
                uh.w[1] = hib ? sh_[b0 + 3] : wh_[b0 + 1];
                uh.w[2] = hib ? wh_[b0 + 2] : sh_[b0 + 0];
                uh.w[3] = hib ? wh_[b0 + 3] : sh_[b0 + 1];
                ul.w[0] = hib ? sl_[b0 + 2] : wl_[b0 + 0];
                ul.w[1] = hib ? sl_[b0 + 3] : wl_[b0 + 1];
                ul.w[2] = hib ? wl_[b0 + 2] : sl_[b0 + 0];
                ul.w[3] = hib ? wl_[b0 + 3] : sl_[b0 + 1];
                const int e8 = (mm * 2 + cc) * 2 + h;   // kv octet
                #pragma unroll
                for (int mdc = 0; mdc < 2; ++mdc) {
                    bf16x8 vhf = lds_frag(sVh, mdc * 32 + qcol, e8);
                    bf16x8 vlf = lds_frag(sVl, mdc * 32 + qcol, e8);
                    accO[mdc] = __builtin_amdgcn_mfma_f32_32x32x16_bf16(vhf, uh.v, accO[mdc], 0, 0, 0);
                    accO[mdc] = __builtin_amdgcn_mfma_f32_32x32x16_bf16(vhf, ul.v, accO[mdc], 0, 0, 0);
                    accO[mdc] = __builtin_amdgcn_mfma_f32_32x32x16_bf16(vlf, uh.v, accO[mdc], 0, 0, 0);
                }
            }
        }
    }

    // ---- epilogue: O^T[d][q] -> bf16 hi/lo planes [token][h*64+d] ----
    const float inv = 1.0f / l_run;
    const int bb = bh >> 4, hh = bh & 15;
    const int ss = q0 + qcol;
    unsigned short* po_h = oh + ((size_t)(bb * S_LEN + ss)) * D_MODEL + hh * HDIM;
    unsigned short* po_l = ol + ((size_t)(bb * S_LEN + ss)) * D_MODEL + hh * HDIM;
    #pragma unroll
    for (int mdc = 0; mdc < 2; ++mdc)
        #pragma unroll
        for (int r = 0; r < 16; r += 2) {
            const int d = mdc * 32 + (r & 3) + 8 * (r >> 2) + 4 * h;
            const float v0 = accO[mdc][r] * inv, v1 = accO[mdc][r + 1] * inv;
            unsigned short h0, l0, h1, l1;
            bf16_split(v0, h0, l0);
            bf16_split(v1, h1, l1);
            *(u32*)(po_h + d) = ((u32)h1 << 16) | h0;
            *(u32*)(po_l + d) = ((u32)l1 << 16) | l0;
        }
}

// ---------------------------------------------------------------------------
extern "C" void kernel_launch(void* const* d_in, const int* in_sizes, int n_in,
                              void* d_out, int out_size, void* d_ws, size_t ws_size,
                              hipStream_t stream)
{
    const float* x     = (const float*)d_in[0];
    const float* w_qkv = (const float*)d_in[1];
    const float* b_qkv = (const float*)d_in[2];
    const float* w_out = (const float*)d_in[3];
    const float* b_out = (const float*)d_in[4];
    float* out = (float*)d_out;

    const int M = NBATCH * S_LEN;  // 4096
    const size_t PL = (size_t)32 * S_LEN * HDIM;   // 4,194,304 elems = 8 MB

    // ws layout (64 MB total; ws_size >= 67.1 MB proven):
    //  [0..8M)   Qh   [8..16) Ql   [16..24) Kh   [24..32) Kl
    //  [32..40)  Vth  [40..48) Vtl [48..56)  xh  [56..64)  xl
    unsigned short* Qh  = (unsigned short*)d_ws;
    unsigned short* Ql  = Qh  + PL;
    unsigned short* Kh  = Ql  + PL;
    unsigned short* Kl  = Kh  + PL;
    unsigned short* Vth = Kl  + PL;
    unsigned short* Vtl = Vth + PL;
    unsigned short* xh  = Vtl + PL;
    unsigned short* xl  = xh  + PL;
    // aliases (stream-ordered reuse):
    unsigned short* wqh = (unsigned short*)d_out;          // dead before gemm2 writes
    unsigned short* wql = wqh + (size_t)DQKV * D_MODEL;
    unsigned short* aoh = xh;                              // x dead after gemm1
    unsigned short* aol = xl;
    unsigned short* woh = Qh;                              // Q planes dead after attn
    unsigned short* wol = Qh + (size_t)D_MODEL * D_MODEL;

    dim3 blk(256);
    split_f32_bf16<<<1024, blk, 0, stream>>>(x, xh, xl, M * D_MODEL / 4);
    split_f32_bf16<<<1024, blk, 0, stream>>>(w_qkv, wqh, wql, DQKV * D_MODEL / 4);

    gemm_mfma_qkv<<<dim3(DQKV / 128, M / 128), blk, 0, stream>>>(
        xh, xl, wqh, wql, b_qkv, Qh, Ql, Kh, Kl, Vth, Vtl, M, DQKV, D_MODEL);

    attn_mfma_kernel<<<dim3(512), blk, 0, stream>>>(Qh, Ql, Kh, Kl, Vth, Vtl, aoh, aol);

    split_f32_bf16<<<512, blk, 0, stream>>>(w_out, woh, wol, D_MODEL * D_MODEL / 4);

    gemm_mfma_split<<<dim3(D_MODEL / 128, M / 128), blk, 0, stream>>>(
        aoh, aol, woh, wol, b_out, out, M, D_MODEL, D_MODEL);
}